// Round 6
// baseline (283.908 us; speedup 1.0000x reference)
//
#include <hip/hip_runtime.h>
#include <hip/hip_bf16.h>
#include <stdint.h>

#define DEVI __device__ __forceinline__

using u16 = unsigned short;
typedef __attribute__((ext_vector_type(8))) _Float16 halfx8;
typedef __attribute__((ext_vector_type(4))) float f32x4;

// Problem dims (fixed by the reference)
constexpr int BB = 4, TT = 2048, CC = 1024, KD = 1024, VD = 1024;
constexpr int QKVW = 3072;                 // fused projection width
constexpr int OUTW = CC + VD;              // 2048
constexpr float INV_SQRT_K = 0.03125f;     // 1/sqrt(1024)

DEVI u16 f2h(float f) {
  _Float16 h = (_Float16)f;
  return __builtin_bit_cast(u16, h);
}

// async global->LDS, 16 B per lane. LDS dest is wave-uniform base + lane*16.
DEVI void gload16(const u16* g, u16* l) {
  __builtin_amdgcn_global_load_lds(
      (const __attribute__((address_space(1))) void*)g,
      (__attribute__((address_space(3))) void*)l, 16, 0, 0);
}

// ---- cast x to f16 (for MFMA) and copy x into out[:, :C] (fp32) ----
__global__ void cast_x_copy(const float* __restrict__ x, u16* __restrict__ xh,
                            float* __restrict__ out) {
  size_t i = (size_t)blockIdx.x * blockDim.x + threadIdx.x;  // over B*T*C/4
  float4 v = reinterpret_cast<const float4*>(x)[i];
  ushort4 u;
  u.x = f2h(v.x); u.y = f2h(v.y); u.z = f2h(v.z); u.w = f2h(v.w);
  reinterpret_cast<ushort4*>(xh)[i] = u;
  size_t e = i * 4;
  size_t bt = e / CC;
  int c = (int)(e % CC);
  *reinterpret_cast<float4*>(&out[bt * OUTW + c]) = v;
}

// ---- W [C,N] f32 -> Wt section [N,C] f16 (dst points at section base) ----
__global__ void transpose_cast_w(const float* __restrict__ W, u16* __restrict__ Wt) {
  __shared__ float tile[32][33];
  int n0 = blockIdx.x * 32, c0 = blockIdx.y * 32;
  int tx = threadIdx.x, ty = threadIdx.y;  // 32 x 8
  for (int i = ty; i < 32; i += 8)
    tile[i][tx] = W[(size_t)(c0 + i) * KD + n0 + tx];
  __syncthreads();
  for (int i = ty; i < 32; i += 8)
    Wt[(size_t)(n0 + i) * CC + c0 + tx] = f2h(tile[tx][i]);
}

// ---- concat biases -> bc[3072] ----
__global__ void concat_bias(const float* __restrict__ bq, const float* __restrict__ bk,
                            const float* __restrict__ bv, float* __restrict__ bc) {
  int n = blockIdx.x * 256 + threadIdx.x;
  float v = (n < 1024) ? bq[n] : (n < 2048) ? bk[n - 1024] : bv[n - 2048];
  bc[n] = v;
}

// ---- V cols of QKV [B*T, 3072] -> Vt [B,VD,T] f16 ----
__global__ void transpose_v(const u16* __restrict__ QKV, u16* __restrict__ Vt) {
  __shared__ u16 tile[32][33];
  int b = blockIdx.z;
  int n0 = blockIdx.x * 32, s0 = blockIdx.y * 32;
  const u16* src = QKV + (size_t)b * TT * QKVW + 2048;  // V columns
  u16* dst = Vt + (size_t)b * VD * TT;
  int tx = threadIdx.x, ty = threadIdx.y;
  for (int i = ty; i < 32; i += 8)
    tile[i][tx] = src[(size_t)(s0 + i) * QKVW + n0 + tx];
  __syncthreads();
  for (int i = ty; i < 32; i += 8)
    dst[(size_t)(n0 + i) * TT + s0 + tx] = tile[tx][i];
}

// ---- 256x256-tile 8-wave f16 MFMA GEMM, fine-phase schedule (T2+T3+T4+T5) ----
// Out = alpha*(A @ Bm^T)(+bias). A:[M,Kd] (lda), Bm:[N,Kd] (ldb), both row-major.
// 3 LDS buffers (BK=32), 2 phases per K-tile, each phase:
//   {ds_read frag subtile || issue 2 global_load_lds for K-tile t+2} ->
//   barrier -> setprio(1) -> 16 MFMA -> setprio(0) -> barrier
// One counted vmcnt(4) per K-tile (never 0 in steady state). Race-free by
// construction: stages target buf (t+2)%3, reads touch buf t%3 only, and the
// end-of-K-tile barrier separates buf reuse by a full K-tile.
// Swizzle (both-sides, rule 21): linear LDS dest; source col-chunk and read
// col-chunk both XORed with (row>>1)&3 -> 2-way max bank aliasing (free).
template <typename OutT, bool CSKIP, bool KLIM, bool BIAS>
__global__ __launch_bounds__(512, 2) void gemm_bt(
    const u16* __restrict__ A, const u16* __restrict__ Bm, OutT* __restrict__ Out,
    const float* __restrict__ bias, int Kd, int lda, int ldb, int ldo,
    long long strA, long long strB, long long strO, float alpha) {
  constexpr int BM = 256, BN = 256, BK = 32;
  __shared__ u16 sA[3 * BM * BK];  // 3 x 16 KB
  __shared__ u16 sB[3 * BN * BK];  // total 96 KB -> 1 block/CU
  const int r0 = blockIdx.x * BM, c0 = blockIdx.y * BN;
  if (CSKIP && c0 > r0 + BM - 1) return;  // tile fully masked; never read downstream
  A   += (size_t)blockIdx.z * strA;
  Bm  += (size_t)blockIdx.z * strB;
  Out += (size_t)blockIdx.z * strO;

  const int tid = threadIdx.x;
  const int lane = tid & 63;
  const int w = tid >> 6;            // 0..7
  const int wm = w >> 2, wn = w & 3; // 2M x 4N wave grid; wave tile 128x64
  const int l15 = lane & 15, l4 = lane >> 4;
  const int cswz8 = 8 * (l4 ^ ((l15 >> 1) & 3));  // swizzled read col (u16)

  // staging map: thread t covers row t>>2 (0..127; +128 for line1), chunk t&3.
  // LDS dest linear (byte t*16); global source chunk pre-swizzled (rule 21).
  const int srow = tid >> 2;
  const int sc8 = 8 * ((tid & 3) ^ ((tid >> 3) & 3));  // == chunk ^ ((srow>>1)&3)
  const u16* gA  = A  + (size_t)(r0 + srow) * lda + sc8;
  const u16* gA2 = gA + (size_t)128 * lda;
  const u16* gB  = Bm + (size_t)(c0 + srow) * ldb + sc8;
  const u16* gB2 = gB + (size_t)128 * ldb;
  const int sdst = tid * 8;  // u16 offset; line1 at +4096

  f32x4 acc[8][4] = {};

  int kmax = Kd;
  if (KLIM) { int km = r0 + BM; kmax = km < Kd ? km : Kd; }
  const int NT = kmax / BK;  // >= 8 at all call sites

  auto stageA = [&](int buf, int kt) {
    const int k0 = kt * BK;
    u16* d = sA + buf * 8192 + sdst;
    gload16(gA + k0, d);
    gload16(gA2 + k0, d + 4096);
  };
  auto stageB = [&](int buf, int kt) {
    const int k0 = kt * BK;
    u16* d = sB + buf * 8192 + sdst;
    gload16(gB + k0, d);
    gload16(gB2 + k0, d + 4096);
  };

  stageA(0, 0); stageB(0, 0);
  stageA(1, 1); stageB(1, 1);
  asm volatile("s_waitcnt vmcnt(4)" ::: "memory");  // K-tile 0 landed (in-order)
  __builtin_amdgcn_s_barrier();

  int buf = 0;
  for (int kt = 0; kt < NT; ++kt) {
    int nb = buf + 2; if (nb >= 3) nb -= 3;  // (kt+2)%3
    const u16* rA = sA + buf * 8192;
    const u16* rB = sB + buf * 8192;
    halfx8 bf[4], af[4];
    // ---- phase alpha: B-frags + A-half0, stage A-lines of kt+2 ----
#pragma unroll
    for (int n = 0; n < 4; ++n)
      bf[n] = *reinterpret_cast<const halfx8*>(&rB[(wn * 64 + n * 16 + l15) * BK + cswz8]);
#pragma unroll
    for (int m = 0; m < 4; ++m)
      af[m] = *reinterpret_cast<const halfx8*>(&rA[(wm * 128 + m * 16 + l15) * BK + cswz8]);
    if (kt + 2 < NT) stageA(nb, kt + 2);
    __builtin_amdgcn_s_barrier();
    __builtin_amdgcn_s_setprio(1);
#pragma unroll
    for (int m = 0; m < 4; ++m)
#pragma unroll
      for (int n = 0; n < 4; ++n)
        acc[m][n] = __builtin_amdgcn_mfma_f32_16x16x32_f16(af[m], bf[n], acc[m][n], 0, 0, 0);
    __builtin_amdgcn_s_setprio(0);
    __builtin_amdgcn_s_barrier();
    // ---- phase beta: A-half1 (B-frags held in regs), stage B-lines of kt+2 ----
#pragma unroll
    for (int m = 0; m < 4; ++m)
      af[m] = *reinterpret_cast<const halfx8*>(&rA[(wm * 128 + (m + 4) * 16 + l15) * BK + cswz8]);
    if (kt + 2 < NT) stageB(nb, kt + 2);
    __builtin_amdgcn_s_barrier();
    __builtin_amdgcn_s_setprio(1);
#pragma unroll
    for (int m = 0; m < 4; ++m)
#pragma unroll
      for (int n = 0; n < 4; ++n)
        acc[m + 4][n] = __builtin_amdgcn_mfma_f32_16x16x32_f16(af[m], bf[n], acc[m + 4][n], 0, 0, 0);
    __builtin_amdgcn_s_setprio(0);
    if (kt + 1 < NT) {
      if (kt + 2 < NT) asm volatile("s_waitcnt vmcnt(4)" ::: "memory");  // kt+1 landed, kt+2 in flight
      else             asm volatile("s_waitcnt vmcnt(0)" ::: "memory");  // drain tail
      __builtin_amdgcn_s_barrier();
    }
    buf = buf + 1; if (buf == 3) buf = 0;
  }

  // epilogue: C/D layout col = lane&15, row = (lane>>4)*4 + reg  [m89/m91 verified]
#pragma unroll
  for (int m = 0; m < 8; ++m) {
    const int growb = r0 + wm * 128 + m * 16 + l4 * 4;
#pragma unroll
    for (int n = 0; n < 4; ++n) {
      const int gcol = c0 + wn * 64 + n * 16 + l15;
      float bvv = 0.f;
      if (BIAS) bvv = bias[gcol];
#pragma unroll
      for (int r = 0; r < 4; ++r) {
        float val = acc[m][n][r] * alpha + bvv;
        size_t off = (size_t)(growb + r) * ldo + gcol;
        if constexpr (sizeof(OutT) == 2) {
          reinterpret_cast<u16*>(Out)[off] = f2h(val);
        } else {
          reinterpret_cast<float*>(Out)[off] = val;
        }
      }
    }
  }
}

// ---- column softmax over t (axis=1), masked to t >= s ----
constexpr int NCH = 32;
constexpr int TCH = TT / NCH;  // 64
__global__ void stats_partial(const float* __restrict__ S, float* __restrict__ Mp,
                              float* __restrict__ Dp) {
  int b = blockIdx.z;
  int s = blockIdx.x * 256 + threadIdx.x;
  int s0 = blockIdx.x * 256;
  int t0 = blockIdx.y * TCH;
  int idx = (blockIdx.y * BB + b) * TT + s;
  float m = -1e30f, d = 0.f;
  if (t0 + TCH - 1 >= s0) {
    const float* Sb = S + (size_t)b * TT * TT;
    if (t0 >= s0 + 255) {  // chunk fully below diagonal for every column in block
      for (int t = t0; t < t0 + TCH; ++t)
        m = fmaxf(m, Sb[(size_t)t * TT + s]);
      for (int t = t0; t < t0 + TCH; ++t)
        d += __expf(Sb[(size_t)t * TT + s] - m);
    } else {
      for (int t = t0; t < t0 + TCH; ++t)
        if (t >= s) m = fmaxf(m, Sb[(size_t)t * TT + s]);
      for (int t = t0; t < t0 + TCH; ++t)
        if (t >= s) d += __expf(Sb[(size_t)t * TT + s] - m);
    }
  }
  Mp[idx] = m;
  Dp[idx] = d;
}

__global__ void stats_combine(const float* __restrict__ Mp, const float* __restrict__ Dp,
                              float* __restrict__ Mc, float* __restrict__ Di) {
  int b = blockIdx.y;
  int s = blockIdx.x * 256 + threadIdx.x;
  float m = -1e30f;
  for (int c = 0; c < NCH; ++c) m = fmaxf(m, Mp[(c * BB + b) * TT + s]);
  float d = 0.f;
  for (int c = 0; c < NCH; ++c)
    d += Dp[(c * BB + b) * TT + s] * __expf(Mp[(c * BB + b) * TT + s] - m);
  Mc[b * TT + s] = m;
  Di[b * TT + s] = 1.f / d;  // column always contains the diagonal -> d >= 1
}

// P[t,s] = exp(S[t,s]-M[s])/D[s] for t>=s else 0, f16. PV tiles are 256 deep now.
constexpr int ATCH = 64;
__global__ void softmax_apply(const float* __restrict__ S, const float* __restrict__ Mc,
                              const float* __restrict__ Di, u16* __restrict__ P) {
  int b = blockIdx.z;
  int s = blockIdx.x * 256 + threadIdx.x;
  int s0 = blockIdx.x * 256;
  int t0 = blockIdx.y * ATCH;
  if (s0 > ((t0 + ATCH - 1) | 255)) return;  // outside any PV-read tile band (BM=256)
  const float* Sb = S + (size_t)b * TT * TT;
  u16* Pb = P + (size_t)b * TT * TT;
  float m = Mc[b * TT + s], di = Di[b * TT + s];
  for (int t = t0; t < t0 + ATCH; ++t) {
    float p = 0.f;
    if (t >= s) p = __expf(Sb[(size_t)t * TT + s] - m) * di;
    Pb[(size_t)t * TT + s] = f2h(p);
  }
}

extern "C" void kernel_launch(void* const* d_in, const int* in_sizes, int n_in,
                              void* d_out, int out_size, void* d_ws, size_t ws_size,
                              hipStream_t stream) {
  const float* x  = (const float*)d_in[0];
  const float* Wq = (const float*)d_in[1];
  const float* bq = (const float*)d_in[2];
  const float* Wk = (const float*)d_in[3];
  const float* bk = (const float*)d_in[4];
  const float* Wv = (const float*)d_in[5];
  const float* bv = (const float*)d_in[6];
  float* out = (float*)d_out;
  char* ws = (char*)d_ws;
  constexpr size_t MB = 1024ull * 1024ull;

  // Workspace layout (max 135 MB), sequential-reuse aliases:
  u16* xh   = (u16*)(ws);              // 16 MB  [B*T, C] f16   (dead after proj)
  u16* QKV  = (u16*)(ws + 16 * MB);    // 48 MB  [B*T, 3072] f16: Q|K|V columns
  u16* Wt   = (u16*)(ws + 64 * MB);    // 6 MB   [3072, C] f16  (dead after proj)
  float* bc = (float*)(ws + 70 * MB);  // 12 KB  concat bias
  float* S  = (float*)(ws + 71 * MB);  // 64 MB  [B,T,T] fp32 logits
  u16* Vt = xh;                        // alias: [B,VD,T] f16
  u16* P  = QKV;                       // alias: QKV dead after transpose_v+S; 32 MB
  float* Mp = (float*)(ws + 64 * MB);  // alias Wt (dead): 1 MB [NCH,B,T]
  float* Dp = (float*)(ws + 65 * MB);  // 1 MB
  float* Mc = (float*)(ws + 66 * MB);  // 32 KB [B,T]
  float* Di = (float*)(ws + 66 * MB + 64 * 1024);  // 32 KB

  cast_x_copy<<<dim3((BB * TT * CC / 4) / 256), dim3(256), 0, stream>>>(x, xh, out);
  dim3 tb(32, 8);
  transpose_cast_w<<<dim3(KD / 32, CC / 32), tb, 0, stream>>>(Wq, Wt);
  transpose_cast_w<<<dim3(KD / 32, CC / 32), tb, 0, stream>>>(Wk, Wt + 1024 * 1024);
  transpose_cast_w<<<dim3(VD / 32, CC / 32), tb, 0, stream>>>(Wv, Wt + 2048 * 1024);
  concat_bias<<<dim3(QKVW / 256), 256, 0, stream>>>(bq, bk, bv, bc);

  // fused projection: QKV = xh @ Wt^T + bc  -> f16 [8192, 3072]
  gemm_bt<u16, false, false, true><<<dim3(32, 12, 1), 512, 0, stream>>>(
      xh, Wt, QKV, bc, CC, CC, CC, QKVW, 0, 0, 0, 1.f);

  transpose_v<<<dim3(VD / 32, TT / 32, BB), tb, 0, stream>>>(QKV, Vt);

  // S = (Q @ K^T) / sqrt(K), fully-masked tiles skipped
  gemm_bt<float, true, false, false><<<dim3(TT / 256, TT / 256, BB), 512, 0, stream>>>(
      QKV, QKV + 1024, S, nullptr, KD, QKVW, QKVW, TT,
      (long long)TT * QKVW, (long long)TT * QKVW, (long long)TT * TT, INV_SQRT_K);

  // column softmax over t (axis=1)
  stats_partial<<<dim3(TT / 256, NCH, BB), 256, 0, stream>>>(S, Mp, Dp);
  stats_combine<<<dim3(TT / 256, BB), 256, 0, stream>>>(Mp, Dp, Mc, Di);
  softmax_apply<<<dim3(TT / 256, TT / ATCH, BB), 256, 0, stream>>>(S, Mc, Di, P);

  // read = P @ V (= P @ Vt^T), K truncated at r0+256 (exact: P==0 above diag)
  gemm_bt<float, false, true, false><<<dim3(TT / 256, VD / 256, BB), 512, 0, stream>>>(
      P, Vt, out + CC, nullptr, TT, TT, TT, OUTW,
      (long long)TT * TT, (long long)VD * TT, (long long)TT * OUTW, 1.f);
}

// Round 7
// 255.160 us; speedup vs baseline: 1.1127x; 1.1127x over previous
//
#include <hip/hip_runtime.h>
#include <hip/hip_bf16.h>
#include <stdint.h>

#define DEVI __device__ __forceinline__

using u16 = unsigned short;
typedef __attribute__((ext_vector_type(8))) _Float16 halfx8;
typedef __attribute__((ext_vector_type(4))) float f32x4;

// Problem dims (fixed by the reference)
constexpr int BB = 4, TT = 2048, CC = 1024, KD = 1024, VD = 1024;
constexpr int QKVW = 3072;                 // fused projection width
constexpr int OUTW = CC + VD;              // 2048
constexpr float INV_SQRT_K = 0.03125f;     // 1/sqrt(1024)

DEVI u16 f2h(float f) {
  _Float16 h = (_Float16)f;
  return __builtin_bit_cast(u16, h);
}

// async global->LDS, 16 B per lane. LDS dest is wave-uniform base + lane*16.
DEVI void gload16(const u16* g, u16* l) {
  __builtin_amdgcn_global_load_lds(
      (const __attribute__((address_space(1))) void*)g,
      (__attribute__((address_space(3))) void*)l, 16, 0, 0);
}

// ---- cast x to f16 (for MFMA) and copy x into out[:, :C] (fp32) ----
__global__ void cast_x_copy(const float* __restrict__ x, u16* __restrict__ xh,
                            float* __restrict__ out) {
  size_t i = (size_t)blockIdx.x * blockDim.x + threadIdx.x;  // over B*T*C/4
  float4 v = reinterpret_cast<const float4*>(x)[i];
  ushort4 u;
  u.x = f2h(v.x); u.y = f2h(v.y); u.z = f2h(v.z); u.w = f2h(v.w);
  reinterpret_cast<ushort4*>(xh)[i] = u;
  size_t e = i * 4;
  size_t bt = e / CC;
  int c = (int)(e % CC);
  *reinterpret_cast<float4*>(&out[bt * OUTW + c]) = v;
}

// ---- W [C,N] f32 -> Wt section [N,C] f16 (dst points at section base) ----
__global__ void transpose_cast_w(const float* __restrict__ W, u16* __restrict__ Wt) {
  __shared__ float tile[32][33];
  int n0 = blockIdx.x * 32, c0 = blockIdx.y * 32;
  int tx = threadIdx.x, ty = threadIdx.y;  // 32 x 8
  for (int i = ty; i < 32; i += 8)
    tile[i][tx] = W[(size_t)(c0 + i) * KD + n0 + tx];
  __syncthreads();
  for (int i = ty; i < 32; i += 8)
    Wt[(size_t)(n0 + i) * CC + c0 + tx] = f2h(tile[tx][i]);
}

// ---- concat biases -> bc[3072] ----
__global__ void concat_bias(const float* __restrict__ bq, const float* __restrict__ bk,
                            const float* __restrict__ bv, float* __restrict__ bc) {
  int n = blockIdx.x * 256 + threadIdx.x;
  float v = (n < 1024) ? bq[n] : (n < 2048) ? bk[n - 1024] : bv[n - 2048];
  bc[n] = v;
}

// ---- V cols of QKV [B*T, 3072] -> Vt [B,VD,T] f16 ----
__global__ void transpose_v(const u16* __restrict__ QKV, u16* __restrict__ Vt) {
  __shared__ u16 tile[32][33];
  int b = blockIdx.z;
  int n0 = blockIdx.x * 32, s0 = blockIdx.y * 32;
  const u16* src = QKV + (size_t)b * TT * QKVW + 2048;  // V columns
  u16* dst = Vt + (size_t)b * VD * TT;
  int tx = threadIdx.x, ty = threadIdx.y;
  for (int i = ty; i < 32; i += 8)
    tile[i][tx] = src[(size_t)(s0 + i) * QKVW + n0 + tx];
  __syncthreads();
  for (int i = ty; i < 32; i += 8)
    dst[(size_t)(n0 + i) * TT + s0 + tx] = tile[tx][i];
}

// ---- 256xBN-tile 8-wave f16 MFMA GEMM, 1-barrier/K-tile counted-vmcnt loop ----
// Out = alpha*(A @ Bm^T)(+bias). A:[M,Kd] (lda), Bm:[N,Kd] (ldb), row-major.
// 3 LDS buffers, BK=32. Per K-tile kt:
//   { ds_read all frags (buf kt%3) || issue LPT global_load_lds for kt+2 ->
//     buf (kt+2)%3; setprio(1); MR*NR MFMA; setprio(0); vmcnt(LPT); barrier }
// Race-free: stage(kt+2) overwrites buf[(kt-1)%3], whose ds_reads completed
// before kt-1's end barrier (reads precede that wave's MFMA; barrier joins all).
// vmcnt(LPT) at kt's end = kt+1's loads landed, kt+2's still in flight (never
// drains to 0 in steady state). Compiler auto-interleaves ds_read/MFMA inside
// the phase (visible deps); waves drift up to a K-tile apart -> LDS pipe and
// MFMA pipe overlap across waves; setprio biases arbitration toward MFMA.
// Swizzle (both-sides, rule 21): linear LDS dest; source col-chunk and read
// col-chunk both XORed with (row>>1)&3 -> conflict-free b128 (verified R5: 0).
template <typename OutT, int BN, bool CSKIP, bool KLIM, bool BIAS>
__global__ __launch_bounds__(512, 2) void gemm_bt(
    const u16* __restrict__ A, const u16* __restrict__ Bm, OutT* __restrict__ Out,
    const float* __restrict__ bias, int Kd, int lda, int ldb, int ldo,
    long long strA, long long strB, long long strO, float alpha) {
  constexpr int BM = 256, BK = 32;
  constexpr int WM = (BN == 256) ? 2 : 4, WN = 8 / WM;  // wave grid
  constexpr int WR = BM / WM, WC = BN / WN;             // wave tile (128x64 / 64x64)
  constexpr int MR = WR / 16, NR = WC / 16;             // frags per wave
  constexpr int BLINES = BN / 128;                      // B stage lines (2 or 1)
  constexpr int LPT = 2 + BLINES;                       // loads/thread/K-tile
  constexpr int ASZ = BM * BK, BSZ = BN * BK;           // u16 per buffer
  __shared__ u16 sA[3 * ASZ];
  __shared__ u16 sB[3 * BSZ];
  const int r0 = blockIdx.x * BM, c0 = blockIdx.y * BN;
  if (CSKIP && c0 > r0 + BM - 1) return;  // tile fully masked; never read downstream
  A   += (size_t)blockIdx.z * strA;
  Bm  += (size_t)blockIdx.z * strB;
  Out += (size_t)blockIdx.z * strO;

  const int tid = threadIdx.x;
  const int lane = tid & 63;
  const int w = tid >> 6;            // 0..7
  const int wm = w / WN, wn = w % WN;
  const int l15 = lane & 15, l4 = lane >> 4;
  const int cswz8 = 8 * (l4 ^ ((l15 >> 1) & 3));  // swizzled read col (u16)

  // staging map: thread t covers row t>>2 (0..127; +128 for A line1), chunk t&3.
  // LDS dest linear (byte t*16); global source chunk pre-swizzled (rule 21).
  const int srow = tid >> 2;
  const int sc8 = 8 * ((tid & 3) ^ ((tid >> 3) & 3));  // chunk ^ ((srow>>1)&3)
  const u16* gA  = A  + (size_t)(r0 + srow) * lda + sc8;
  const u16* gA2 = gA + (size_t)128 * lda;
  const u16* gB  = Bm + (size_t)(c0 + srow) * ldb + sc8;
  const u16* gB2 = gB + (size_t)128 * ldb;  // unused when BLINES==1
  const int sdst = tid * 8;  // u16 offset; line1 at +4096

  f32x4 acc[MR][NR] = {};

  int kmax = Kd;
  if (KLIM) { int km = r0 + BM; kmax = km < Kd ? km : Kd; }
  const int NT = kmax / BK;  // >= 8 at all call sites

  auto stage = [&](int buf, int kt) {
    const int k0 = kt * BK;
    u16* da = sA + buf * ASZ + sdst;
    gload16(gA + k0, da);
    gload16(gA2 + k0, da + 4096);
    u16* db = sB + buf * BSZ + sdst;
    gload16(gB + k0, db);
    if (BLINES == 2) gload16(gB2 + k0, db + 4096);
  };

  stage(0, 0);
  stage(1, 1);
  if constexpr (LPT == 4) asm volatile("s_waitcnt vmcnt(4)" ::: "memory");
  else                    asm volatile("s_waitcnt vmcnt(3)" ::: "memory");
  __builtin_amdgcn_s_barrier();

  int buf = 0;
  for (int kt = 0; kt < NT; ++kt) {
    int nb = buf + 2; if (nb >= 3) nb -= 3;  // (kt+2)%3
    const u16* rA = sA + buf * ASZ;
    const u16* rB = sB + buf * BSZ;
    halfx8 af[MR], bfv[NR];
#pragma unroll
    for (int n = 0; n < NR; ++n)
      bfv[n] = *reinterpret_cast<const halfx8*>(&rB[(wn * WC + n * 16 + l15) * BK + cswz8]);
#pragma unroll
    for (int m = 0; m < MR; ++m)
      af[m] = *reinterpret_cast<const halfx8*>(&rA[(wm * WR + m * 16 + l15) * BK + cswz8]);
    if (kt + 2 < NT) stage(nb, kt + 2);
    __builtin_amdgcn_s_setprio(1);
#pragma unroll
    for (int m = 0; m < MR; ++m)
#pragma unroll
      for (int n = 0; n < NR; ++n)
        acc[m][n] = __builtin_amdgcn_mfma_f32_16x16x32_f16(af[m], bfv[n], acc[m][n], 0, 0, 0);
    __builtin_amdgcn_s_setprio(0);
    if (kt + 2 < NT) {
      if constexpr (LPT == 4) asm volatile("s_waitcnt vmcnt(4)" ::: "memory");
      else                    asm volatile("s_waitcnt vmcnt(3)" ::: "memory");
    } else if (kt + 1 < NT) {
      asm volatile("s_waitcnt vmcnt(0)" ::: "memory");  // drain tail
    }
    if (kt + 1 < NT) __builtin_amdgcn_s_barrier();
    buf = buf + 1; if (buf == 3) buf = 0;
  }

  // epilogue: C/D layout col = lane&15, row = (lane>>4)*4 + reg  [m89/m91 verified]
#pragma unroll
  for (int m = 0; m < MR; ++m) {
    const int growb = r0 + wm * WR + m * 16 + l4 * 4;
#pragma unroll
    for (int n = 0; n < NR; ++n) {
      const int gcol = c0 + wn * WC + n * 16 + l15;
      float bvv = 0.f;
      if (BIAS) bvv = bias[gcol];
#pragma unroll
      for (int r = 0; r < 4; ++r) {
        float val = acc[m][n][r] * alpha + bvv;
        size_t off = (size_t)(growb + r) * ldo + gcol;
        if constexpr (sizeof(OutT) == 2) {
          reinterpret_cast<u16*>(Out)[off] = f2h(val);
        } else {
          reinterpret_cast<float*>(Out)[off] = val;
        }
      }
    }
  }
}

// ---- column softmax over t (axis=1), masked to t >= s ----
constexpr int NCH = 32;
constexpr int TCH = TT / NCH;  // 64
__global__ void stats_partial(const float* __restrict__ S, float* __restrict__ Mp,
                              float* __restrict__ Dp) {
  int b = blockIdx.z;
  int s = blockIdx.x * 256 + threadIdx.x;
  int s0 = blockIdx.x * 256;
  int t0 = blockIdx.y * TCH;
  int idx = (blockIdx.y * BB + b) * TT + s;
  float m = -1e30f, d = 0.f;
  if (t0 + TCH - 1 >= s0) {
    const float* Sb = S + (size_t)b * TT * TT;
    if (t0 >= s0 + 255) {  // chunk fully below diagonal for every column in block
      for (int t = t0; t < t0 + TCH; ++t)
        m = fmaxf(m, Sb[(size_t)t * TT + s]);
      for (int t = t0; t < t0 + TCH; ++t)
        d += __expf(Sb[(size_t)t * TT + s] - m);
    } else {
      for (int t = t0; t < t0 + TCH; ++t)
        if (t >= s) m = fmaxf(m, Sb[(size_t)t * TT + s]);
      for (int t = t0; t < t0 + TCH; ++t)
        if (t >= s) d += __expf(Sb[(size_t)t * TT + s] - m);
    }
  }
  Mp[idx] = m;
  Dp[idx] = d;
}

__global__ void stats_combine(const float* __restrict__ Mp, const float* __restrict__ Dp,
                              float* __restrict__ Mc, float* __restrict__ Di) {
  int b = blockIdx.y;
  int s = blockIdx.x * 256 + threadIdx.x;
  float m = -1e30f;
  for (int c = 0; c < NCH; ++c) m = fmaxf(m, Mp[(c * BB + b) * TT + s]);
  float d = 0.f;
  for (int c = 0; c < NCH; ++c)
    d += Dp[(c * BB + b) * TT + s] * __expf(Mp[(c * BB + b) * TT + s] - m);
  Mc[b * TT + s] = m;
  Di[b * TT + s] = 1.f / d;  // column always contains the diagonal -> d >= 1
}

// P[t,s] = exp(S[t,s]-M[s])/D[s] for t>=s else 0, f16. PV tiles are 256 deep.
constexpr int ATCH = 64;
__global__ void softmax_apply(const float* __restrict__ S, const float* __restrict__ Mc,
                              const float* __restrict__ Di, u16* __restrict__ P) {
  int b = blockIdx.z;
  int s = blockIdx.x * 256 + threadIdx.x;
  int s0 = blockIdx.x * 256;
  int t0 = blockIdx.y * ATCH;
  if (s0 > ((t0 + ATCH - 1) | 255)) return;  // outside any PV-read tile band (BM=256)
  const float* Sb = S + (size_t)b * TT * TT;
  u16* Pb = P + (size_t)b * TT * TT;
  float m = Mc[b * TT + s], di = Di[b * TT + s];
  for (int t = t0; t < t0 + ATCH; ++t) {
    float p = 0.f;
    if (t >= s) p = __expf(Sb[(size_t)t * TT + s] - m) * di;
    Pb[(size_t)t * TT + s] = f2h(p);
  }
}

extern "C" void kernel_launch(void* const* d_in, const int* in_sizes, int n_in,
                              void* d_out, int out_size, void* d_ws, size_t ws_size,
                              hipStream_t stream) {
  const float* x  = (const float*)d_in[0];
  const float* Wq = (const float*)d_in[1];
  const float* bq = (const float*)d_in[2];
  const float* Wk = (const float*)d_in[3];
  const float* bk = (const float*)d_in[4];
  const float* Wv = (const float*)d_in[5];
  const float* bv = (const float*)d_in[6];
  float* out = (float*)d_out;
  char* ws = (char*)d_ws;
  constexpr size_t MB = 1024ull * 1024ull;

  // Workspace layout (max 135 MB), sequential-reuse aliases:
  u16* xh   = (u16*)(ws);              // 16 MB  [B*T, C] f16   (dead after proj)
  u16* QKV  = (u16*)(ws + 16 * MB);    // 48 MB  [B*T, 3072] f16: Q|K|V columns
  u16* Wt   = (u16*)(ws + 64 * MB);    // 6 MB   [3072, C] f16  (dead after proj)
  float* bc = (float*)(ws + 70 * MB);  // 12 KB  concat bias
  float* S  = (float*)(ws + 71 * MB);  // 64 MB  [B,T,T] fp32 logits
  u16* Vt = xh;                        // alias: [B,VD,T] f16
  u16* P  = QKV;                       // alias: QKV dead after transpose_v+S; 32 MB
  float* Mp = (float*)(ws + 64 * MB);  // alias Wt (dead): 1 MB [NCH,B,T]
  float* Dp = (float*)(ws + 65 * MB);  // 1 MB
  float* Mc = (float*)(ws + 66 * MB);  // 32 KB [B,T]
  float* Di = (float*)(ws + 66 * MB + 64 * 1024);  // 32 KB

  cast_x_copy<<<dim3((BB * TT * CC / 4) / 256), dim3(256), 0, stream>>>(x, xh, out);
  dim3 tb(32, 8);
  transpose_cast_w<<<dim3(KD / 32, CC / 32), tb, 0, stream>>>(Wq, Wt);
  transpose_cast_w<<<dim3(KD / 32, CC / 32), tb, 0, stream>>>(Wk, Wt + 1024 * 1024);
  transpose_cast_w<<<dim3(VD / 32, CC / 32), tb, 0, stream>>>(Wv, Wt + 2048 * 1024);
  concat_bias<<<dim3(QKVW / 256), 256, 0, stream>>>(bq, bk, bv, bc);

  // fused projection: QKV = xh @ Wt^T + bc  -> f16 [8192, 3072]
  gemm_bt<u16, 256, false, false, true><<<dim3(32, 12, 1), 512, 0, stream>>>(
      xh, Wt, QKV, bc, CC, CC, CC, QKVW, 0, 0, 0, 1.f);

  transpose_v<<<dim3(VD / 32, TT / 32, BB), tb, 0, stream>>>(QKV, Vt);

  // S = (Q @ K^T) / sqrt(K), fully-masked tiles skipped
  gemm_bt<float, 256, true, false, false><<<dim3(TT / 256, TT / 256, BB), 512, 0, stream>>>(
      QKV, QKV + 1024, S, nullptr, KD, QKVW, QKVW, TT,
      (long long)TT * QKVW, (long long)TT * QKVW, (long long)TT * TT, INV_SQRT_K);

  // column softmax over t (axis=1)
  stats_partial<<<dim3(TT / 256, NCH, BB), 256, 0, stream>>>(S, Mp, Dp);
  stats_combine<<<dim3(TT / 256, BB), 256, 0, stream>>>(Mp, Dp, Mc, Di);
  softmax_apply<<<dim3(TT / 256, TT / ATCH, BB), 256, 0, stream>>>(S, Mc, Di, P);

  // read = P @ V (= P @ Vt^T), BN=128 -> grid 256 blocks (full GPU), K
  // truncated at r0+256 (exact: P==0 above diag)
  gemm_bt<float, 128, false, true, false><<<dim3(TT / 256, VD / 128, BB), 512, 0, stream>>>(
      P, Vt, out + CC, nullptr, TT, TT, TT, OUTW,
      (long long)TT * TT, (long long)VD * TT, (long long)TT * OUTW, 1.f);
}